// Round 3
// baseline (1208.023 us; speedup 1.0000x reference)
//
#include <hip/hip_runtime.h>
#include <hip/hip_bf16.h>
#include <stdint.h>

#define HD   1024
#define BB   64
#define SS   2048
#define MT   (BB*SS)          // 131072 rows
#define NEGV -10000000000.0f

typedef __attribute__((ext_vector_type(8))) short bf16x8;
typedef __attribute__((ext_vector_type(4))) float f32x4;
typedef __attribute__((ext_vector_type(4))) int   i32x4;

__device__ __forceinline__ void gll16(const void* g, void* l) {
  __builtin_amdgcn_global_load_lds((const __attribute__((address_space(1))) void*)g,
                                   (__attribute__((address_space(3))) void*)l, 16, 0, 0);
}

// tanh via native exp + v_rcp_f32 (1-ulp approx): 1 - 2/(e^{2x}+1).
__device__ __forceinline__ float tanh_fast(float x) {
  float e = __expf(2.0f * x);
  return 1.0f - 2.0f * __builtin_amdgcn_rcpf(e + 1.0f);
}

// ---------------------------------------------------------------------------
// Swizzled bf16 LDS layout (A and B identical): within a 128-row x 64-k half-
// tile, element (l, k=j*8+e) lives at byte  l*128 + ((j ^ (l&7))<<4) + e*2.
// Fragment reads (b128 of 8 consecutive k) are 2-way bank aliased (free).
// B half-tiles are PRE-TILED in global memory (16 KB contiguous, linear order)
// so global_load_lds stages them directly.  A is read as fp32 from enc,
// converted in VGPRs and ds_write'n with the swizzle applied per-lane
// (write pattern is bank-uniform: 8 lanes per 16B slot = b128 floor).
// ---------------------------------------------------------------------------

// ---------------------------------------------------------------------------
// Prep kernel (small): one dispatch.
//   blocks [0,128)        : re-tile We = W_attn[H:2H]^T into swizzled bf16
//   blocks [128,1152)     : dpb[b][n] = b_attn[n] + dec[b]@Wd[:,n]
//   blocks [1152,1280)    : zero logits
// ---------------------------------------------------------------------------
__global__ void __launch_bounds__(256) prep_small(
    const float* __restrict__ Wattn, __hip_bfloat16* __restrict__ wet,
    const float* __restrict__ dec, const float* __restrict__ battn,
    float* __restrict__ dpb, float* __restrict__ logits) {
  __shared__ float red[4][64];
  int tid = threadIdx.x;
  int bid = blockIdx.x;

  if (bid < 128) {
    // ---- prep_we: direct transpose re-tile; W is L2/L3-resident ----
    int nt = bid >> 4, kc = bid & 15;
    const float* src = Wattn + (size_t)(HD + kc*64)*HD + nt*128;
    size_t base = (size_t)bid * 8192;
    #pragma unroll 4
    for (int i = 0; i < 32; ++i) {
      int lin = i*256 + tid;
      int nl = lin >> 6, j = (lin >> 3) & 7, e = lin & 7;
      int kk = ((j ^ (nl & 7)) << 3) + e;
      wet[base + lin] = __float2bfloat16(src[(size_t)kk*HD + nl]);
    }
    return;
  }
  bid -= 128;

  if (bid < 1024) {
    // ---- prep_dpb ----
    int b = bid >> 4, n0 = (bid & 15) * 64;
    int nn = tid & 63, kg = tid >> 6;
    const float* wp = Wattn + (size_t)(kg*256)*HD + n0 + nn;
    const float* dp = dec + b*HD + kg*256;
    float acc = 0.0f;
    #pragma unroll 8
    for (int h = 0; h < 256; ++h) acc += dp[h] * wp[(size_t)h*HD];
    red[kg][nn] = acc;
    __syncthreads();
    if (tid < 64) {
      int n = n0 + tid;
      dpb[b*HD + n] = battn[n] + red[0][tid] + red[1][tid]
                               + red[2][tid] + red[3][tid];
    }
    return;
  }
  bid -= 1024;

  // ---- zero logits: 128 blocks x 4KB ----
  f32x4 z = {0.f, 0.f, 0.f, 0.f};
  *(f32x4*)(logits + (size_t)bid*1024 + tid*4) = z;
}

// ---------------------------------------------------------------------------
// GEMM (fused): 256x256 tile, BK=64, 512 thr (8 waves 2x4), 8-phase schedule,
// double-buffered 128 KiB LDS, counted vmcnt, setprio around MFMA clusters.
// A operand: fp32 read DIRECTLY from enc -> cvt_pk -> swizzled ds_write
// (no bf16 E workspace).  B operand: global_load_lds from pre-tiled wet.
// Fused epilogue: tanh(C + dpb) . v_w -> atomicAdd logits.
//
// Pipeline (steady state, tile t, buf = t&1):
//   PH1: gll B(t+1) both halves -> buf[~t]; read A0,B0; MFMA(0,0)
//   PH2: read B1;                                      MFMA(0,1)
//   PH3: read A1; vmcnt(4) -> ds_write A(t+1)->buf[~t]; MFMA(1,1)
//   PH4: read B0; issue A(t+2) fp32 loads;             MFMA(1,0); vmcnt(8)
// vmcnt accounting (retire in issue order):
//   at PH3: outstanding = A(t+1)8 [PH4(t-1)] + B(t+1)4 [PH1(t)] -> wait 4
//   at PH4: outstanding = B(t+1)4 + A(t+2)8 (just issued)       -> wait 8
// Edges: prologue loads+writes A(0),A(1) and stages B(0);
//   t=0 PH3 skips write; t=14 PH4 drains to vmcnt(0); t=15 stages nothing.
// ---------------------------------------------------------------------------
__global__ void __launch_bounds__(512, 2) gemm_fused_8ph(
    const float* __restrict__ enc, const __hip_bfloat16* __restrict__ Wt,
    const float* __restrict__ dpb, const float* __restrict__ vw,
    float* __restrict__ logits) {
  __shared__ __align__(16) char lds[131072];   // [buf:2][op:2(A,B)][half:2][16KB]

  int tid = threadIdx.x;
  int lane = tid & 63, wid = tid >> 6;
  int wm = wid & 1, wn = wid >> 1;              // 2 x 4 wave grid
  int lane15 = lane & 15, kg = lane >> 4;

  // XCD-aware decode: 2048 blocks = 8 xcd * (64 bm * 4 bn), bn fastest.
  int x = blockIdx.x & 7, r = blockIdx.x >> 3;
  int bm = x*64 + (r >> 2);                     // 0..511
  int bn = r & 3;                               // 0..3
  int m0 = bm << 8, n0 = bn << 8;

  f32x4 acc[2][2][4][2];                        // [hr][hc][mf][nf]
  #pragma unroll
  for (int i = 0; i < 2; ++i)
    #pragma unroll
    for (int j = 0; j < 2; ++j)
      #pragma unroll
      for (int k = 0; k < 4; ++k)
        #pragma unroll
        for (int l = 0; l < 2; ++l)
          acc[i][j][k][l] = (f32x4){0.f, 0.f, 0.f, 0.f};

  bf16x8 af[4][2], bfr[2][2];

  // ---- A reg-staging geometry: thread (rA = tid>>2, qA = tid&3) owns ----
  // ---- rows {rA, rA+128}, k-octets {2qA, 2qA+1} = 16 consecutive k.   ----
  int rA = tid >> 2, qA = tid & 3;
  const float* encR0 = enc + ((size_t)(m0 + rA))*HD + qA*16;
  const float* encR1 = enc + ((size_t)(m0 + 128 + rA))*HD + qA*16;
  int swA = (rA & 7) << 4;
  int wo0 = ((qA*2    ) << 4) ^ swA;            // swizzled 16B slot, octet 2qA
  int wo1 = ((qA*2 + 1) << 4) ^ swA;            // octet 2qA+1

  f32x4 aP[8], aQ[8];

  auto loadA = [&](int t2, f32x4 (&d)[8]) {
    const float* p0 = encR0 + t2*64;
    const float* p1 = encR1 + t2*64;
    d[0] = *(const f32x4*)(p0);      d[1] = *(const f32x4*)(p0 + 4);
    d[2] = *(const f32x4*)(p0 + 8);  d[3] = *(const f32x4*)(p0 + 12);
    d[4] = *(const f32x4*)(p1);      d[5] = *(const f32x4*)(p1 + 4);
    d[6] = *(const f32x4*)(p1 + 8);  d[7] = *(const f32x4*)(p1 + 12);
  };
  auto writeA = [&](int tw, f32x4 (&s)[8]) {    // 4 x ds_write_b128, swizzled
    char* b0 = lds + ((tw & 1) << 16) + rA*128;
    char* b1 = b0 + 16384;
    union { __hip_bfloat162 h[4]; i32x4 q; } c0, c1, c2, c3;
    c0.h[0] = __float22bfloat162_rn(make_float2(s[0].x, s[0].y));
    c0.h[1] = __float22bfloat162_rn(make_float2(s[0].z, s[0].w));
    c0.h[2] = __float22bfloat162_rn(make_float2(s[1].x, s[1].y));
    c0.h[3] = __float22bfloat162_rn(make_float2(s[1].z, s[1].w));
    c1.h[0] = __float22bfloat162_rn(make_float2(s[2].x, s[2].y));
    c1.h[1] = __float22bfloat162_rn(make_float2(s[2].z, s[2].w));
    c1.h[2] = __float22bfloat162_rn(make_float2(s[3].x, s[3].y));
    c1.h[3] = __float22bfloat162_rn(make_float2(s[3].z, s[3].w));
    c2.h[0] = __float22bfloat162_rn(make_float2(s[4].x, s[4].y));
    c2.h[1] = __float22bfloat162_rn(make_float2(s[4].z, s[4].w));
    c2.h[2] = __float22bfloat162_rn(make_float2(s[5].x, s[5].y));
    c2.h[3] = __float22bfloat162_rn(make_float2(s[5].z, s[5].w));
    c3.h[0] = __float22bfloat162_rn(make_float2(s[6].x, s[6].y));
    c3.h[1] = __float22bfloat162_rn(make_float2(s[6].z, s[6].w));
    c3.h[2] = __float22bfloat162_rn(make_float2(s[7].x, s[7].y));
    c3.h[3] = __float22bfloat162_rn(make_float2(s[7].z, s[7].w));
    *(i32x4*)(b0 + wo0) = c0.q;
    *(i32x4*)(b0 + wo1) = c1.q;
    *(i32x4*)(b1 + wo0) = c2.q;
    *(i32x4*)(b1 + wo1) = c3.q;
  };
  auto stageB = [&](int h, int t) {             // 2 x global_load_lds (16B)
    const char* g = (const char*)Wt + (((size_t)(bn*2 + h)*16 + t) << 14);
    char* l = lds + ((t & 1) << 16) + (1 << 15) + (h << 14);
    gll16(g + (size_t)(wid*64 + lane)*16,     l + wid*1024);
    gll16(g + (size_t)((8+wid)*64 + lane)*16, l + (8+wid)*1024);
  };
  auto readA = [&](int hr, int t) {             // 8 x ds_read_b128
    const char* b = lds + ((t & 1) << 16) + (hr << 14);
    #pragma unroll
    for (int mf = 0; mf < 4; ++mf) {
      int ll = wm*64 + mf*16 + lane15;
      const char* rp = b + ll*128;
      int sw = (ll & 7) << 4;
      af[mf][0] = *(const bf16x8*)(rp + ((kg << 4) ^ sw));
      af[mf][1] = *(const bf16x8*)(rp + (((4 + kg) << 4) ^ sw));
    }
  };
  auto readB = [&](int hc, int t) {             // 4 x ds_read_b128
    const char* b = lds + ((t & 1) << 16) + 32768 + (hc << 14);
    #pragma unroll
    for (int nf = 0; nf < 2; ++nf) {
      int ll = wn*32 + nf*16 + lane15;
      const char* rp = b + ll*128;
      int sw = (ll & 7) << 4;
      bfr[nf][0] = *(const bf16x8*)(rp + ((kg << 4) ^ sw));
      bfr[nf][1] = *(const bf16x8*)(rp + (((4 + kg) << 4) ^ sw));
    }
  };

#define MFMA_PH(HR, HC) do {                                                   \
    __builtin_amdgcn_s_setprio(1);                                             \
    _Pragma("unroll")                                                          \
    for (int kk = 0; kk < 2; ++kk)                                             \
      _Pragma("unroll")                                                        \
      for (int mf = 0; mf < 4; ++mf)                                           \
        _Pragma("unroll")                                                      \
        for (int nf = 0; nf < 2; ++nf)                                         \
          acc[HR][HC][mf][nf] = __builtin_amdgcn_mfma_f32_16x16x32_bf16(       \
              af[mf][kk], bfr[nf][kk], acc[HR][HC][mf][nf], 0, 0, 0);          \
    __builtin_amdgcn_s_setprio(0);                                             \
    __builtin_amdgcn_sched_barrier(0);                                         \
  } while (0)

#define PH_SYNC() do {                                                         \
    __builtin_amdgcn_s_barrier();                                              \
    asm volatile("s_waitcnt lgkmcnt(0)");                                      \
    __builtin_amdgcn_sched_barrier(0);                                         \
  } while (0)

  // ---- Prologue: A(0),A(1) via regs; B(0) via gll. ----
  loadA(0, aP);                                  // 8 vmem
  loadA(1, aQ);                                  // 8 vmem
  stageB(0, 0); stageB(1, 0);                    // 4 vmem
  asm volatile("s_waitcnt vmcnt(12)" ::: "memory");  // A(0) landed
  __builtin_amdgcn_sched_barrier(0);
  writeA(0, aP);
  asm volatile("s_waitcnt vmcnt(4)" ::: "memory");   // A(1) landed
  __builtin_amdgcn_sched_barrier(0);
  writeA(1, aQ);
  asm volatile("s_waitcnt vmcnt(0) lgkmcnt(0)" ::: "memory");  // B(0)+writes
  __builtin_amdgcn_s_barrier();

  #pragma unroll 2
  for (int t = 0; t < 16; ++t) {
    // -------- PH1: quad (0,0); reads A0,B0; gll B(t+1) --------
    if (t + 1 < 16) { stageB(0, t + 1); stageB(1, t + 1); }
    readA(0, t); readB(0, t);
    asm volatile("s_waitcnt lgkmcnt(8)");            // partial drain (12 reads)
    PH_SYNC();
    MFMA_PH(0, 0);
    __builtin_amdgcn_s_barrier();

    // -------- PH2: quad (0,1); reads B1 (A cached) --------
    readB(1, t);
    PH_SYNC();
    MFMA_PH(0, 1);
    __builtin_amdgcn_s_barrier();

    // -------- PH3: quad (1,1); reads A1 (B cached); write A(t+1) --------
    readA(1, t);
    if (t >= 1 && t + 1 < 16) {
      asm volatile("s_waitcnt vmcnt(4)" ::: "memory");   // A(t+1) loads done
      __builtin_amdgcn_sched_barrier(0);
      writeA(t + 1, aP);
    }
    PH_SYNC();
    MFMA_PH(1, 1);
    __builtin_amdgcn_s_barrier();

    // -------- PH4: quad (1,0); reads B0; issue A(t+2) loads --------
    readB(0, t);
    if (t + 2 < 16) loadA(t + 2, aP);
    PH_SYNC();
    MFMA_PH(1, 0);
    if (t < 14)       asm volatile("s_waitcnt vmcnt(8)" ::: "memory");
    else if (t == 14) asm volatile("s_waitcnt vmcnt(0)" ::: "memory");
    __builtin_amdgcn_s_barrier();
  }
#undef MFMA_PH
#undef PH_SYNC

  // -------- fused epilogue: tanh(C + dpb) . vw, reduce over n --------
  __syncthreads();
  float* red = (float*)lds;                     // alias tile LDS (reads done)
  if (tid < 256) red[tid] = 0.0f;
  __syncthreads();

  int bidx = m0 >> 11;                          // batch index
  float dpv[2][2], vwv[2][2];
  #pragma unroll
  for (int hc = 0; hc < 2; ++hc)
    #pragma unroll
    for (int nf = 0; nf < 2; ++nf) {
      int n = n0 + hc*128 + wn*32 + nf*16 + lane15;
      dpv[hc][nf] = dpb[bidx*HD + n];
      vwv[hc][nf] = vw[n];
    }

  #pragma unroll
  for (int hr = 0; hr < 2; ++hr)
    #pragma unroll
    for (int mf = 0; mf < 4; ++mf)
      #pragma unroll
      for (int rr = 0; rr < 4; ++rr) {
        float s = 0.0f;
        #pragma unroll
        for (int hc = 0; hc < 2; ++hc)
          #pragma unroll
          for (int nf = 0; nf < 2; ++nf)
            s += tanh_fast(acc[hr][hc][mf][nf][rr] + dpv[hc][nf]) * vwv[hc][nf];
        s += __shfl_xor(s, 1); s += __shfl_xor(s, 2);
        s += __shfl_xor(s, 4); s += __shfl_xor(s, 8);
        if (lane15 == 0) atomicAdd(&red[hr*128 + wm*64 + mf*16 + kg*4 + rr], s);
      }
  __syncthreads();
  if (tid < 256) atomicAdd(&logits[m0 + tid], red[tid]);
}

// ---------------------------------------------------------------------------
// Kernel 4: masked softmax over S per batch row.  mask==1 -> -1e10
// ---------------------------------------------------------------------------
__global__ void softmax_k(const float* __restrict__ logits, const int* __restrict__ mask,
                          float* __restrict__ out) {
  __shared__ float smax[4];
  __shared__ float ssum[4];
  int tid = threadIdx.x, lane = tid & 63, wid = tid >> 6;
  int b = blockIdx.x;
  const float* lg = logits + b*SS;
  const int*   mk = mask   + b*SS;
  f32x4 l0 = *(const f32x4*)(lg + tid*8);
  f32x4 l1 = *(const f32x4*)(lg + tid*8 + 4);
  i32x4 q0 = *(const i32x4*)(mk + tid*8);
  i32x4 q1 = *(const i32x4*)(mk + tid*8 + 4);
  float v[8];
  v[0] = (q0.x == 1) ? NEGV : l0.x;  v[1] = (q0.y == 1) ? NEGV : l0.y;
  v[2] = (q0.z == 1) ? NEGV : l0.z;  v[3] = (q0.w == 1) ? NEGV : l0.w;
  v[4] = (q1.x == 1) ? NEGV : l1.x;  v[5] = (q1.y == 1) ? NEGV : l1.y;
  v[6] = (q1.z == 1) ? NEGV : l1.z;  v[7] = (q1.w == 1) ? NEGV : l1.w;
  float mx = v[0];
  #pragma unroll
  for (int i = 1; i < 8; ++i) mx = fmaxf(mx, v[i]);
  #pragma unroll
  for (int m = 1; m <= 32; m <<= 1) mx = fmaxf(mx, __shfl_xor(mx, m));
  if (lane == 0) smax[wid] = mx;
  __syncthreads();
  mx = fmaxf(fmaxf(smax[0], smax[1]), fmaxf(smax[2], smax[3]));
  float s = 0.0f;
  #pragma unroll
  for (int i = 0; i < 8; ++i) { v[i] = __expf(v[i] - mx); s += v[i]; }
  #pragma unroll
  for (int m = 1; m <= 32; m <<= 1) s += __shfl_xor(s, m);
  if (lane == 0) ssum[wid] = s;
  __syncthreads();
  s = ssum[0] + ssum[1] + ssum[2] + ssum[3];
  float inv = 1.0f / s;
  f32x4 o0 = {v[0]*inv, v[1]*inv, v[2]*inv, v[3]*inv};
  f32x4 o1 = {v[4]*inv, v[5]*inv, v[6]*inv, v[7]*inv};
  *(f32x4*)(out + b*SS + tid*8)     = o0;
  *(f32x4*)(out + b*SS + tid*8 + 4) = o1;
}

// ---------------------------------------------------------------------------
extern "C" void kernel_launch(void* const* d_in, const int* in_sizes, int n_in,
                              void* d_out, int out_size, void* d_ws, size_t ws_size,
                              hipStream_t stream) {
  const float* dec   = (const float*)d_in[0];   // (B, H)
  const float* enc   = (const float*)d_in[1];   // (B, S, H)
  const int*   mask  = (const int*)  d_in[2];   // (B, S)
  const float* Wattn = (const float*)d_in[3];   // (2H, H)
  const float* battn = (const float*)d_in[4];   // (H)
  const float* vw    = (const float*)d_in[5];   // (H)
  float* out = (float*)d_out;

  char* ws = (char*)d_ws;
  __hip_bfloat16* wet = (__hip_bfloat16*)ws;                  // 2 MB
  float* dpb    = (float*)(ws + (2u<<20));                    // 256 KB
  float* logits = (float*)(ws + (2u<<20) + (256u<<10));       // 512 KB

  prep_small<<<1280, 256, 0, stream>>>(Wattn, wet, dec, battn, dpb, logits);
  gemm_fused_8ph<<<2048, 512, 0, stream>>>(enc, wet, dpb, vw, logits);
  softmax_k<<<BB, 256, 0, stream>>>(logits, mask, out);
}